// Round 19
// baseline (212.069 us; speedup 1.0000x reference)
//
#include <hip/hip_runtime.h>

typedef _Float16 half4 __attribute__((ext_vector_type(4)));
typedef _Float16 half8 __attribute__((ext_vector_type(8)));
typedef float    f32x4 __attribute__((ext_vector_type(4)));
typedef unsigned int u32x2 __attribute__((ext_vector_type(2)));
typedef unsigned int u32x4 __attribute__((ext_vector_type(4)));

__device__ __forceinline__ unsigned int pkrtz(float a, float b) {
    return __builtin_bit_cast(unsigned int, __builtin_amdgcn_cvt_pkrtz(a, b));
}
__device__ __forceinline__ half4 pack4(float a, float b, float c, float d) {
    u32x2 t; t[0] = pkrtz(a, b); t[1] = pkrtz(c, d);
    return __builtin_bit_cast(half4, t);
}
__device__ __forceinline__ half8 pack8(float a, float b, float c, float d,
                                       float e, float f, float gg, float h) {
    u32x4 t; t[0] = pkrtz(a, b); t[1] = pkrtz(c, d);
    t[2] = pkrtz(e, f); t[3] = pkrtz(gg, h);
    return __builtin_bit_cast(half8, t);
}
// Bare v_exp_f32 (no ocml denormal fixup). Safe: sacc <= 12 (vote-guarded),
// >= ~-40, so result is normal and cannot overflow.
__device__ __forceinline__ float fexp2(float x) {
    return __builtin_amdgcn_exp2f(x);
}

#define ROWF 256   // floats per token row (H*d = 4*64)
#define HDIM 64

// intra-tile token offset: j = tt*64 + th*8 + tw  ->  2304*tt + 48*th + tw
__device__ __forceinline__ int intra_off(int j) {
    return 2304 * (j >> 6) + 48 * ((j >> 3) & 7) + (j & 7);
}

// K LDS row permutation within each 32-key group: LDS row 16jt+4g+r holds
// key 8g+4jt+r. Then S^T output (C/D row = 4g+r) gives lane (g,c) keys
// s*32 + 8g + e (e = 4jt+r) = exactly the PV 16x16x32 A-fragment order.
__device__ __forceinline__ int kperm32(int x) {
    return ((x & 4) << 2) | ((x & 24) >> 1) | (x & 3);
}

__global__ __launch_bounds__(512) void sta_kernel(
    const float* __restrict__ qg, const float* __restrict__ kg,
    const float* __restrict__ vg, float* __restrict__ out)
{
    // single-buffered; XOR 16B-unit swizzle (unit ^= (row>>1)&7) on all sides
    __shared__ _Float16 Klds[128 * 64];   // [row perm32(key)][d] 128B rows
    __shared__ _Float16 Vlds[64 * 128];   // transposed [d][key] 256B rows

    const int tid  = threadIdx.x;
    const int wave = tid >> 6;    // 0..7 : q rows wave*48..+47
    const int lane = tid & 63;
    const int g    = lane >> 4;   // 0..3
    const int c    = lane & 15;   // 0..15
    const int csw  = c >> 1;      // read-side swizzle key ((row>>1)&7 == c>>1)

    // balanced dispatch: groups of 4 = one tile's 4 heads (27 cost-units),
    // head rotated per tile so cost has no period-8 (XCD round-robin) alias
    const int bid  = blockIdx.x;
    const int tile = bid >> 2;
    const int head = (bid + tile) & 3;

    const int nt = tile / 36;
    const int nh = (tile / 6) % 6;
    const int nw = tile % 6;
    const int tbase = 13824 * nt + 384 * nh + 8 * nw;

    // --- window-start base + packed per-window-tile kb deltas (16b each) ---
    int W, kb0; unsigned long long dpk;
    const int t0 = nt < 4 ? nt : 4;
    const int h0 = nh < 4 ? nh : 4;
    const int w0 = nw < 4 ? nw : 4;
    if (head == 0) {        // (2,1,1)
        W = 2; kb0 = 13824 * t0 + 384 * nh + 8 * nw; dpk = (13824ULL << 16);
    } else if (head == 1) { // (1,2,2)
        W = 4; kb0 = 13824 * nt + 384 * h0 + 8 * w0;
        dpk = (8ULL << 16) | (384ULL << 32) | (392ULL << 48);
    } else if (head == 2) { // (1,1,2)
        W = 2; kb0 = 13824 * nt + 384 * nh + 8 * w0; dpk = (8ULL << 16);
    } else {                // (1,1,1)
        W = 1; kb0 = tbase; dpk = 0ULL;
    }
    const int NC = W * 3;   // 128-key chunks

    // --- Q fragments: lane holds Q[q = wave*48 + mt*16 + c][d-slice] ---
    const float qscale = 0.125f * 1.44269504f;   // 1/sqrt(64) * log2(e)
    half8 qf[3][2];
    #pragma unroll
    for (int mt = 0; mt < 3; ++mt) {
        const int j = wave * 48 + mt * 16 + c;
        const float* qp = qg + (size_t)(tbase + intra_off(j)) * ROWF + head * HDIM;
        #pragma unroll
        for (int kc = 0; kc < 2; ++kc) {
            f32x4 a = *(const f32x4*)(qp + kc * 32 + g * 8);
            f32x4 b = *(const f32x4*)(qp + kc * 32 + g * 8 + 4);
            qf[mt][kc] = pack8(a[0] * qscale, a[1] * qscale, a[2] * qscale, a[3] * qscale,
                               b[0] * qscale, b[1] * qscale, b[2] * qscale, b[3] * qscale);
        }
    }

    // ones B-operand for the l row-sum MFMA (constant, register-only)
    u32x4 onep; onep[0] = onep[1] = onep[2] = onep[3] = 0x3C003C00u;
    const half8 ones8 = __builtin_bit_cast(half8, onep);

    f32x4 oacc[3][4];
    f32x4 lacc[3];          // row-sum accumulator, same row domain as oacc (q=g*4+r)
    float m_r[3];           // per-row anchor (exp2 domain), folded into MFMA C-init
    #pragma unroll
    for (int mt = 0; mt < 3; ++mt) {
        #pragma unroll
        for (int dt = 0; dt < 4; ++dt) oacc[mt][dt] = (f32x4){0.f, 0.f, 0.f, 0.f};
        lacc[mt] = (f32x4){0.f, 0.f, 0.f, 0.f};
        m_r[mt] = 8.0f;
    }

    const int r4  = tid >> 4;   // key group of 4 (0..31) within 128-key chunk
    const int sc4 = tid & 15;   // d group of 4 (0..15)

    int toff0, toff1, toff2, toff3, krow0;
    {
        const int r0 = r4 * 4;
        toff0 = intra_off(r0 + 0);
        toff1 = intra_off(r0 + 1);
        toff2 = intra_off(r0 + 2);
        toff3 = intra_off(r0 + 3);
        krow0 = (r0 & 96) + kperm32(r0 & 31);   // permuted LDS row (32-key groups)
    }
    const size_t lin = (size_t)head * HDIM + sc4 * 4;

    f32x4 kr0, kr1, kr2, kr3, vr0, vr1, vr2, vr3;

#define ISSUE_N(N) do {                                                  \
        const int wi_ = (N) / 3;                                         \
        const int kb_ = kb0 + (int)((dpk >> (wi_ * 16)) & 0xFFFFULL)     \
                            + 4608 * ((N) - wi_ * 3);                    \
        const size_t a0 = (size_t)(kb_ + toff0) * ROWF + lin;            \
        const size_t a1 = (size_t)(kb_ + toff1) * ROWF + lin;            \
        const size_t a2 = (size_t)(kb_ + toff2) * ROWF + lin;            \
        const size_t a3 = (size_t)(kb_ + toff3) * ROWF + lin;            \
        kr0 = *(const f32x4*)(kg + a0); vr0 = *(const f32x4*)(vg + a0);  \
        kr1 = *(const f32x4*)(kg + a1); vr1 = *(const f32x4*)(vg + a1);  \
        kr2 = *(const f32x4*)(kg + a2); vr2 = *(const f32x4*)(vg + a2);  \
        kr3 = *(const f32x4*)(kg + a3); vr3 = *(const f32x4*)(vg + a3);  \
    } while (0)

#define COMMIT() do {                                                        \
        _Pragma("unroll")                                                    \
        for (int j = 0; j < 4; ++j) {                                        \
            const int kr_ = krow0 + j;                                       \
            const int ko_ = kr_ * 64 +                                       \
                (((sc4 >> 1) ^ ((kr_ >> 1) & 7)) << 3) + ((sc4 & 1) << 2);   \
            const f32x4 kv = (j == 0) ? kr0 : (j == 1) ? kr1                 \
                             : (j == 2) ? kr2 : kr3;                         \
            *(half4*)&Klds[ko_] = pack4(kv[0], kv[1], kv[2], kv[3]);         \
        }                                                                    \
        _Pragma("unroll")                                                    \
        for (int e = 0; e < 4; ++e) {                                        \
            const int vr_ = sc4 * 4 + e;                                     \
            const int vo_ = vr_ * 128 +                                      \
                (((r4 >> 1) ^ ((vr_ >> 1) & 7)) << 3) + ((r4 & 1) << 2);     \
            *(half4*)&Vlds[vo_] = pack4(vr0[e], vr1[e], vr2[e], vr3[e]);     \
        }                                                                    \
    } while (0)

    ISSUE_N(0);

    for (int ci = 0; ci < NC; ++ci) {
        COMMIT();          // vmcnt satisfied: loads issued >=1 compute phase ago
        __syncthreads();
        if (ci + 1 < NC) ISSUE_N(ci + 1);   // overlap next chunk's HBM latency

        #pragma unroll
        for (int s = 0; s < 4; ++s) {       // four 32-key sub-blocks
            // --- S^T - m = K*Q^T + C(-m); kf read ONCE, used by all 3 mt ---
            f32x4 sacc[3][2];
            #pragma unroll
            for (int mt = 0; mt < 3; ++mt) {
                const float nm = -m_r[mt];
                sacc[mt][0] = (f32x4){nm, nm, nm, nm};
                sacc[mt][1] = (f32x4){nm, nm, nm, nm};
            }
            #pragma unroll
            for (int kc = 0; kc < 2; ++kc) {
                #pragma unroll
                for (int jt = 0; jt < 2; ++jt) {
                    const half8 kf = *(const half8*)
                        &Klds[(s * 32 + jt * 16 + c) * 64 + (((kc * 4 + g) ^ csw) << 3)];
                    #pragma unroll
                    for (int mt = 0; mt < 3; ++mt)
                        sacc[mt][jt] = __builtin_amdgcn_mfma_f32_16x16x32_f16(
                            kf, qf[mt][kc], sacc[mt][jt], 0, 0, 0);
                }
            }

            // --- softmax per mt: exp2 first; fmax tree + vote in parallel ---
            half8 pa[3];
            #pragma unroll
            for (int mt = 0; mt < 3; ++mt) {
                float p0 = fexp2(sacc[mt][0][0]), p1 = fexp2(sacc[mt][0][1]);
                float p2 = fexp2(sacc[mt][0][2]), p3 = fexp2(sacc[mt][0][3]);
                float p4 = fexp2(sacc[mt][1][0]), p5 = fexp2(sacc[mt][1][1]);
                float p6 = fexp2(sacc[mt][1][2]), p7 = fexp2(sacc[mt][1][3]);
                const float ma = fmaxf(fmaxf(sacc[mt][0][0], sacc[mt][0][1]),
                                       fmaxf(sacc[mt][0][2], sacc[mt][0][3]));
                const float mb = fmaxf(fmaxf(sacc[mt][1][0], sacc[mt][1][1]),
                                       fmaxf(sacc[mt][1][2], sacc[mt][1][3]));
                const float mm = fmaxf(ma, mb);

                if (__builtin_expect(!__all(mm <= 12.f), 0)) {
                    // slow path: row-max reduce, shift anchor, rescale p and state
                    float mrow = mm;
                    mrow = fmaxf(mrow, __shfl_xor(mrow, 16, 64));
                    mrow = fmaxf(mrow, __shfl_xor(mrow, 32, 64));
                    const float delta = fmaxf(mrow, 0.f);
                    const float alpha = fexp2(-delta);   // row q=c
                    m_r[mt] += delta;
                    p0 *= alpha; p1 *= alpha; p2 *= alpha; p3 *= alpha;
                    p4 *= alpha; p5 *= alpha; p6 *= alpha; p7 *= alpha;
                    float ar[4];
                    #pragma unroll
                    for (int r = 0; r < 4; ++r) ar[r] = __shfl(alpha, g * 4 + r, 16);
                    #pragma unroll
                    for (int r = 0; r < 4; ++r) {
                        lacc[mt][r] *= ar[r];
                        #pragma unroll
                        for (int dt = 0; dt < 4; ++dt)
                            oacc[mt][dt][r] *= ar[r];
                    }
                }

                pa[mt] = pack8(p0, p1, p2, p3, p4, p5, p6, p7);
            }

            // --- O += P V (vb read ONCE per dt, used by 3 mt); l += P*ones ---
            #pragma unroll
            for (int mt = 0; mt < 3; ++mt)
                lacc[mt] = __builtin_amdgcn_mfma_f32_16x16x32_f16(
                    pa[mt], ones8, lacc[mt], 0, 0, 0);
            #pragma unroll
            for (int dt = 0; dt < 4; ++dt) {
                const half8 vb = *(const half8*)
                    &Vlds[(dt * 16 + c) * 128 + ((((s << 2) | g) ^ csw) << 3)];
                #pragma unroll
                for (int mt = 0; mt < 3; ++mt)
                    oacc[mt][dt] = __builtin_amdgcn_mfma_f32_16x16x32_f16(
                        pa[mt], vb, oacc[mt][dt], 0, 0, 0);
            }
        }
        __syncthreads();
    }
#undef ISSUE_N
#undef COMMIT

    // --- epilogue: lacc already in oacc row domain; normalize, scatter via untile ---
    #pragma unroll
    for (int mt = 0; mt < 3; ++mt) {
        #pragma unroll
        for (int r = 0; r < 4; ++r) {
            const int j = wave * 48 + mt * 16 + g * 4 + r;
            float* op = out + (size_t)(tbase + intra_off(j)) * ROWF + head * HDIM;
            const float linv = __builtin_amdgcn_rcpf(lacc[mt][r]);
            #pragma unroll
            for (int dt = 0; dt < 4; ++dt)
                op[dt * 16 + c] = oacc[mt][dt][r] * linv;
        }
    }
}

extern "C" void kernel_launch(void* const* d_in, const int* in_sizes, int n_in,
                              void* d_out, int out_size, void* d_ws, size_t ws_size,
                              hipStream_t stream) {
    const float* q = (const float*)d_in[0];
    const float* k = (const float*)d_in[1];
    const float* v = (const float*)d_in[2];
    float* o = (float*)d_out;
    dim3 grid(216 * 4);     // groups of 4 = one tile's 4 heads, head rotated
    dim3 block(512);        // 8 waves x 48 q-rows = 384
    hipLaunchKernelGGL(sta_kernel, grid, block, 0, stream, q, k, v, o);
}

// Round 20
// 137.173 us; speedup vs baseline: 1.5460x; 1.5460x over previous
//
#include <hip/hip_runtime.h>

typedef _Float16 half4 __attribute__((ext_vector_type(4)));
typedef _Float16 half8 __attribute__((ext_vector_type(8)));
typedef float    f32x4 __attribute__((ext_vector_type(4)));
typedef unsigned int u32x2 __attribute__((ext_vector_type(2)));
typedef unsigned int u32x4 __attribute__((ext_vector_type(4)));

__device__ __forceinline__ unsigned int pkrtz(float a, float b) {
    return __builtin_bit_cast(unsigned int, __builtin_amdgcn_cvt_pkrtz(a, b));
}
__device__ __forceinline__ half4 pack4(float a, float b, float c, float d) {
    u32x2 t; t[0] = pkrtz(a, b); t[1] = pkrtz(c, d);
    return __builtin_bit_cast(half4, t);
}
__device__ __forceinline__ half8 pack8(float a, float b, float c, float d,
                                       float e, float f, float gg, float h) {
    u32x4 t; t[0] = pkrtz(a, b); t[1] = pkrtz(c, d);
    t[2] = pkrtz(e, f); t[3] = pkrtz(gg, h);
    return __builtin_bit_cast(half8, t);
}
// Bare v_exp_f32 (no ocml denormal fixup). Safe: sacc <= 12 (vote-guarded),
// >= ~-40, so result is normal and cannot overflow.
__device__ __forceinline__ float fexp2(float x) {
    return __builtin_amdgcn_exp2f(x);
}

#define ROWF 256   // floats per token row (H*d = 4*64)
#define HDIM 64
#define NWORK 864  // 216 tiles x 4 heads

// intra-tile token offset: j = tt*64 + th*8 + tw  ->  2304*tt + 48*th + tw
__device__ __forceinline__ int intra_off(int j) {
    return 2304 * (j >> 6) + 48 * ((j >> 3) & 7) + (j & 7);
}

// K LDS row permutation within each 32-key group: LDS row 16jt+4g+r holds
// key 8g+4jt+r -> S^T lands as the PV 16x16x32 A-fragment order.
__device__ __forceinline__ int kperm32(int x) {
    return ((x & 4) << 2) | ((x & 24) >> 1) | (x & 3);
}

__global__ __launch_bounds__(512) void sta_kernel(
    const float* __restrict__ qg, const float* __restrict__ kg,
    const float* __restrict__ vg, float* __restrict__ out,
    int* __restrict__ wcnt)
{
    // single-buffered; XOR 16B-unit swizzle (unit ^= (row>>1)&7) on all sides
    __shared__ _Float16 Klds[128 * 64];   // [row perm32(key)][d] 128B rows
    __shared__ _Float16 Vlds[64 * 128];   // transposed [d][key] 256B rows
    __shared__ int s_w;

    const int tid  = threadIdx.x;
    const int wave = tid >> 6;    // 0..7 : q rows wave*48..+47
    const int lane = tid & 63;
    const int g    = lane >> 4;   // 0..3
    const int c    = lane & 15;   // 0..15
    const int csw  = c >> 1;      // read-side swizzle key ((row>>1)&7 == c>>1)

    const int r4  = tid >> 4;     // key group of 4 (0..31) within 128-key chunk
    const int sc4 = tid & 15;     // d group of 4 (0..15)

    int toff0, toff1, toff2, toff3, krow0;
    {
        const int r0 = r4 * 4;
        toff0 = intra_off(r0 + 0);
        toff1 = intra_off(r0 + 1);
        toff2 = intra_off(r0 + 2);
        toff3 = intra_off(r0 + 3);
        krow0 = (r0 & 96) + kperm32(r0 & 31);   // permuted LDS row (32-key groups)
    }
    const float qscale = 0.125f * 1.44269504f;  // 1/sqrt(64) * log2(e)

    f32x4 kr0, kr1, kr2, kr3, vr0, vr1, vr2, vr3;

    // persistent work-stealing loop: items heavy-first (LPT)
    for (;;) {
        __syncthreads();                 // all lanes done with prev s_w & LDS
        if (tid == 0) s_w = atomicAdd(wcnt, 1);
        __syncthreads();
        const int w = s_w;
        if (w >= NWORK) return;          // uniform exit

        const int hidx = w / 216;        // 0..3, heavy first
        const int tile = w - hidx * 216;
        const int head = (hidx == 0) ? 1 : (hidx == 1 ? 0 : hidx);

        const int nt = tile / 36;
        const int nh = (tile / 6) % 6;
        const int nw = tile % 6;
        const int tbase = 13824 * nt + 384 * nh + 8 * nw;

        // --- window-start base + packed per-window-tile kb deltas ---
        int W, kb0; unsigned long long dpk;
        const int t0 = nt < 4 ? nt : 4;
        const int h0 = nh < 4 ? nh : 4;
        const int w0 = nw < 4 ? nw : 4;
        if (head == 0) {        // (2,1,1)
            W = 2; kb0 = 13824 * t0 + 384 * nh + 8 * nw; dpk = (13824ULL << 16);
        } else if (head == 1) { // (1,2,2)
            W = 4; kb0 = 13824 * nt + 384 * h0 + 8 * w0;
            dpk = (8ULL << 16) | (384ULL << 32) | (392ULL << 48);
        } else if (head == 2) { // (1,1,2)
            W = 2; kb0 = 13824 * nt + 384 * nh + 8 * w0; dpk = (8ULL << 16);
        } else {                // (1,1,1)
            W = 1; kb0 = tbase; dpk = 0ULL;
        }
        const int NC = W * 3;   // 128-key chunks

        // --- Q fragments: lane holds Q[q = wave*48 + mt*16 + c][d-slice] ---
        half8 qf[3][2];
        #pragma unroll
        for (int mt = 0; mt < 3; ++mt) {
            const int j = wave * 48 + mt * 16 + c;
            const float* qp = qg + (size_t)(tbase + intra_off(j)) * ROWF + head * HDIM;
            #pragma unroll
            for (int kc = 0; kc < 2; ++kc) {
                f32x4 a = *(const f32x4*)(qp + kc * 32 + g * 8);
                f32x4 b = *(const f32x4*)(qp + kc * 32 + g * 8 + 4);
                qf[mt][kc] = pack8(a[0] * qscale, a[1] * qscale, a[2] * qscale, a[3] * qscale,
                                   b[0] * qscale, b[1] * qscale, b[2] * qscale, b[3] * qscale);
            }
        }

        f32x4 oacc[3][4];
        float m_r[3], l_r[3];   // anchor + PER-LANE partial row-sum (q=c domain)
        #pragma unroll
        for (int mt = 0; mt < 3; ++mt) {
            #pragma unroll
            for (int dt = 0; dt < 4; ++dt) oacc[mt][dt] = (f32x4){0.f, 0.f, 0.f, 0.f};
            m_r[mt] = 8.0f;
            l_r[mt] = 0.f;
        }

        const size_t lin = (size_t)head * HDIM + sc4 * 4;

#define ISSUE_N(N) do {                                                  \
        const int wi_ = (N) / 3;                                         \
        const int kb_ = kb0 + (int)((dpk >> (wi_ * 16)) & 0xFFFFULL)     \
                            + 4608 * ((N) - wi_ * 3);                    \
        const size_t a0 = (size_t)(kb_ + toff0) * ROWF + lin;            \
        const size_t a1 = (size_t)(kb_ + toff1) * ROWF + lin;            \
        const size_t a2 = (size_t)(kb_ + toff2) * ROWF + lin;            \
        const size_t a3 = (size_t)(kb_ + toff3) * ROWF + lin;            \
        kr0 = *(const f32x4*)(kg + a0); vr0 = *(const f32x4*)(vg + a0);  \
        kr1 = *(const f32x4*)(kg + a1); vr1 = *(const f32x4*)(vg + a1);  \
        kr2 = *(const f32x4*)(kg + a2); vr2 = *(const f32x4*)(vg + a2);  \
        kr3 = *(const f32x4*)(kg + a3); vr3 = *(const f32x4*)(vg + a3);  \
    } while (0)

#define COMMIT() do {                                                        \
        _Pragma("unroll")                                                    \
        for (int j = 0; j < 4; ++j) {                                        \
            const int kr_ = krow0 + j;                                       \
            const int ko_ = kr_ * 64 +                                       \
                (((sc4 >> 1) ^ ((kr_ >> 1) & 7)) << 3) + ((sc4 & 1) << 2);   \
            const f32x4 kv = (j == 0) ? kr0 : (j == 1) ? kr1                 \
                             : (j == 2) ? kr2 : kr3;                         \
            *(half4*)&Klds[ko_] = pack4(kv[0], kv[1], kv[2], kv[3]);         \
        }                                                                    \
        _Pragma("unroll")                                                    \
        for (int e = 0; e < 4; ++e) {                                        \
            const int vr_ = sc4 * 4 + e;                                     \
            const int vo_ = vr_ * 128 +                                      \
                (((r4 >> 1) ^ ((vr_ >> 1) & 7)) << 3) + ((r4 & 1) << 2);     \
            *(half4*)&Vlds[vo_] = pack4(vr0[e], vr1[e], vr2[e], vr3[e]);     \
        }                                                                    \
    } while (0)

        ISSUE_N(0);

        for (int ci = 0; ci < NC; ++ci) {
            COMMIT();
            __syncthreads();
            if (ci + 1 < NC) ISSUE_N(ci + 1);   // overlap next chunk's HBM latency

            #pragma unroll
            for (int s = 0; s < 4; ++s) {       // four 32-key sub-blocks
                // --- S^T - m = K*Q^T + C(-m); kf read ONCE, used by all 3 mt ---
                f32x4 sacc[3][2];
                #pragma unroll
                for (int mt = 0; mt < 3; ++mt) {
                    const float nm = -m_r[mt];
                    sacc[mt][0] = (f32x4){nm, nm, nm, nm};
                    sacc[mt][1] = (f32x4){nm, nm, nm, nm};
                }
                #pragma unroll
                for (int kc = 0; kc < 2; ++kc) {
                    #pragma unroll
                    for (int jt = 0; jt < 2; ++jt) {
                        const half8 kf = *(const half8*)
                            &Klds[(s * 32 + jt * 16 + c) * 64 + (((kc * 4 + g) ^ csw) << 3)];
                        #pragma unroll
                        for (int mt = 0; mt < 3; ++mt)
                            sacc[mt][jt] = __builtin_amdgcn_mfma_f32_16x16x32_f16(
                                kf, qf[mt][kc], sacc[mt][jt], 0, 0, 0);
                    }
                }

                // --- softmax per mt: exp2 first; fmax tree + vote in parallel ---
                half8 pa[3];
                #pragma unroll
                for (int mt = 0; mt < 3; ++mt) {
                    float p0 = fexp2(sacc[mt][0][0]), p1 = fexp2(sacc[mt][0][1]);
                    float p2 = fexp2(sacc[mt][0][2]), p3 = fexp2(sacc[mt][0][3]);
                    float p4 = fexp2(sacc[mt][1][0]), p5 = fexp2(sacc[mt][1][1]);
                    float p6 = fexp2(sacc[mt][1][2]), p7 = fexp2(sacc[mt][1][3]);
                    const float ma = fmaxf(fmaxf(sacc[mt][0][0], sacc[mt][0][1]),
                                           fmaxf(sacc[mt][0][2], sacc[mt][0][3]));
                    const float mb = fmaxf(fmaxf(sacc[mt][1][0], sacc[mt][1][1]),
                                           fmaxf(sacc[mt][1][2], sacc[mt][1][3]));
                    const float mm = fmaxf(ma, mb);

                    if (__builtin_expect(!__all(mm <= 12.f), 0)) {
                        // slow path: row-max reduce, shift anchor, rescale p/state
                        float mrow = mm;
                        mrow = fmaxf(mrow, __shfl_xor(mrow, 16, 64));
                        mrow = fmaxf(mrow, __shfl_xor(mrow, 32, 64));
                        const float delta = fmaxf(mrow, 0.f);
                        const float alpha = fexp2(-delta);   // row q=c
                        m_r[mt] += delta;
                        l_r[mt] *= alpha;
                        p0 *= alpha; p1 *= alpha; p2 *= alpha; p3 *= alpha;
                        p4 *= alpha; p5 *= alpha; p6 *= alpha; p7 *= alpha;
                        float ar[4];
                        #pragma unroll
                        for (int r = 0; r < 4; ++r) ar[r] = __shfl(alpha, g * 4 + r, 16);
                        #pragma unroll
                        for (int r = 0; r < 4; ++r)
                            #pragma unroll
                            for (int dt = 0; dt < 4; ++dt)
                                oacc[mt][dt][r] *= ar[r];
                    }

                    l_r[mt] += ((p0 + p1) + (p2 + p3)) + ((p4 + p5) + (p6 + p7));
                    pa[mt] = pack8(p0, p1, p2, p3, p4, p5, p6, p7);
                }

                // --- O += P V: vb read ONCE per dt, used by all 3 mt ---
                #pragma unroll
                for (int dt = 0; dt < 4; ++dt) {
                    const half8 vb = *(const half8*)
                        &Vlds[(dt * 16 + c) * 128 + ((((s << 2) | g) ^ csw) << 3)];
                    #pragma unroll
                    for (int mt = 0; mt < 3; ++mt)
                        oacc[mt][dt] = __builtin_amdgcn_mfma_f32_16x16x32_f16(
                            pa[mt], vb, oacc[mt][dt], 0, 0, 0);
                }
            }
            __syncthreads();
        }
#undef ISSUE_N
#undef COMMIT

        // --- epilogue: reduce per-lane l partials, normalize, scatter ---
        #pragma unroll
        for (int mt = 0; mt < 3; ++mt) {
            float lf = l_r[mt];
            lf += __shfl_xor(lf, 16, 64);
            lf += __shfl_xor(lf, 32, 64);   // full row sum for q=c
            float lq[4];
            #pragma unroll
            for (int r = 0; r < 4; ++r) lq[r] = __shfl(lf, g * 4 + r, 16);
            #pragma unroll
            for (int r = 0; r < 4; ++r) {
                const int j = wave * 48 + mt * 16 + g * 4 + r;
                float* op = out + (size_t)(tbase + intra_off(j)) * ROWF + head * HDIM;
                const float linv = __builtin_amdgcn_rcpf(lq[r]);
                #pragma unroll
                for (int dt = 0; dt < 4; ++dt)
                    op[dt * 16 + c] = oacc[mt][dt][r] * linv;
            }
        }
    }
}

extern "C" void kernel_launch(void* const* d_in, const int* in_sizes, int n_in,
                              void* d_out, int out_size, void* d_ws, size_t ws_size,
                              hipStream_t stream) {
    const float* q = (const float*)d_in[0];
    const float* k = (const float*)d_in[1];
    const float* v = (const float*)d_in[2];
    float* o = (float*)d_out;
    int* wcnt = (int*)d_ws;
    hipMemsetAsync(wcnt, 0, sizeof(int), stream);   // reset work counter (capture-safe)
    dim3 grid(512);    // 2 blocks/CU, all resident: dispatch-order-proof
    dim3 block(512);   // 8 waves x 48 q-rows = 384
    hipLaunchKernelGGL(sta_kernel, grid, block, 0, stream, q, k, v, o, wcnt);
}

// Round 21
// 128.298 us; speedup vs baseline: 1.6529x; 1.0692x over previous
//
#include <hip/hip_runtime.h>

typedef _Float16 half4 __attribute__((ext_vector_type(4)));
typedef _Float16 half8 __attribute__((ext_vector_type(8)));
typedef float    f32x4 __attribute__((ext_vector_type(4)));
typedef unsigned int u32x2 __attribute__((ext_vector_type(2)));
typedef unsigned int u32x4 __attribute__((ext_vector_type(4)));

__device__ __forceinline__ unsigned int pkrtz(float a, float b) {
    return __builtin_bit_cast(unsigned int, __builtin_amdgcn_cvt_pkrtz(a, b));
}
__device__ __forceinline__ half4 pack4(float a, float b, float c, float d) {
    u32x2 t; t[0] = pkrtz(a, b); t[1] = pkrtz(c, d);
    return __builtin_bit_cast(half4, t);
}
__device__ __forceinline__ half8 pack8(float a, float b, float c, float d,
                                       float e, float f, float gg, float h) {
    u32x4 t; t[0] = pkrtz(a, b); t[1] = pkrtz(c, d);
    t[2] = pkrtz(e, f); t[3] = pkrtz(gg, h);
    return __builtin_bit_cast(half8, t);
}
// Bare v_exp_f32 (no ocml denormal fixup). Safe: sacc <= 12 (vote-guarded),
// >= ~-40, so result is normal and cannot overflow.
__device__ __forceinline__ float fexp2(float x) {
    return __builtin_amdgcn_exp2f(x);
}

#define ROWF 256   // floats per token row (H*d = 4*64)
#define HDIM 64

// intra-tile token offset: j = tt*64 + th*8 + tw  ->  2304*tt + 48*th + tw
__device__ __forceinline__ int intra_off(int j) {
    return 2304 * (j >> 6) + 48 * ((j >> 3) & 7) + (j & 7);
}

// K LDS row permutation within each 32-key group: LDS row 16jt+4g+r holds
// key 8g+4jt+r -> S^T lands as the PV 16x16x32 A-fragment order.
__device__ __forceinline__ int kperm32(int x) {
    return ((x & 4) << 2) | ((x & 24) >> 1) | (x & 3);
}

__global__ __launch_bounds__(512) void sta_kernel(
    const float* __restrict__ qg, const float* __restrict__ kg,
    const float* __restrict__ vg, float* __restrict__ out)
{
    // single-buffered; XOR 16B-unit swizzle (unit ^= (row>>1)&7) on all sides
    __shared__ _Float16 Klds[128 * 64];   // [row perm32(key)][d] 128B rows
    __shared__ _Float16 Vlds[64 * 128];   // transposed [d][key] 256B rows

    const int tid  = threadIdx.x;
    const int wave = tid >> 6;    // 0..7 : q rows wave*48..+47
    const int lane = tid & 63;
    const int g    = lane >> 4;   // 0..3
    const int c    = lane & 15;   // 0..15
    const int csw  = c >> 1;      // read-side swizzle key ((row>>1)&7 == c>>1)

    // heavy-first dispatch (round-18 proven): hidx 0 -> head 1 (W=4)
    const int bid  = blockIdx.x;
    const int hidx = bid / 216;
    const int tile = bid - hidx * 216;
    const int head = (hidx == 0) ? 1 : (hidx == 1 ? 0 : hidx);

    const int nt = tile / 36;
    const int nh = (tile / 6) % 6;
    const int nw = tile % 6;
    const int tbase = 13824 * nt + 384 * nh + 8 * nw;

    // --- window-start base + packed per-window-tile kb deltas (16b each) ---
    int W, kb0; unsigned long long dpk;
    const int t0 = nt < 4 ? nt : 4;
    const int h0 = nh < 4 ? nh : 4;
    const int w0 = nw < 4 ? nw : 4;
    if (head == 0) {        // (2,1,1)
        W = 2; kb0 = 13824 * t0 + 384 * nh + 8 * nw; dpk = (13824ULL << 16);
    } else if (head == 1) { // (1,2,2)
        W = 4; kb0 = 13824 * nt + 384 * h0 + 8 * w0;
        dpk = (8ULL << 16) | (384ULL << 32) | (392ULL << 48);
    } else if (head == 2) { // (1,1,2)
        W = 2; kb0 = 13824 * nt + 384 * nh + 8 * w0; dpk = (8ULL << 16);
    } else {                // (1,1,1)
        W = 1; kb0 = tbase; dpk = 0ULL;
    }
    const int NC = W * 3;   // 128-key chunks

    // --- Q fragments: lane holds Q[q = wave*48 + mt*16 + c][d-slice] ---
    const float qscale = 0.125f * 1.44269504f;   // 1/sqrt(64) * log2(e)
    half8 qf[3][2];
    #pragma unroll
    for (int mt = 0; mt < 3; ++mt) {
        const int j = wave * 48 + mt * 16 + c;
        const float* qp = qg + (size_t)(tbase + intra_off(j)) * ROWF + head * HDIM;
        #pragma unroll
        for (int kc = 0; kc < 2; ++kc) {
            f32x4 a = *(const f32x4*)(qp + kc * 32 + g * 8);
            f32x4 b = *(const f32x4*)(qp + kc * 32 + g * 8 + 4);
            qf[mt][kc] = pack8(a[0] * qscale, a[1] * qscale, a[2] * qscale, a[3] * qscale,
                               b[0] * qscale, b[1] * qscale, b[2] * qscale, b[3] * qscale);
        }
    }

    // ones B-operand for the l row-sum MFMA (constant, register-only)
    u32x4 onep; onep[0] = onep[1] = onep[2] = onep[3] = 0x3C003C00u;
    const half8 ones8 = __builtin_bit_cast(half8, onep);

    f32x4 oacc[3][4];
    f32x4 lacc[3];          // row-sum accumulator, same row domain as oacc (q=g*4+r)
    float m_r[3];           // per-row anchor (exp2 domain), folded into MFMA C-init
    #pragma unroll
    for (int mt = 0; mt < 3; ++mt) {
        #pragma unroll
        for (int dt = 0; dt < 4; ++dt) oacc[mt][dt] = (f32x4){0.f, 0.f, 0.f, 0.f};
        lacc[mt] = (f32x4){0.f, 0.f, 0.f, 0.f};
        m_r[mt] = 8.0f;
    }

    const int r4  = tid >> 4;   // key group of 4 (0..31) within 128-key chunk
    const int sc4 = tid & 15;   // d group of 4 (0..15)

    int toff0, toff1, toff2, toff3, krow0;
    {
        const int r0 = r4 * 4;
        toff0 = intra_off(r0 + 0);
        toff1 = intra_off(r0 + 1);
        toff2 = intra_off(r0 + 2);
        toff3 = intra_off(r0 + 3);
        krow0 = (r0 & 96) + kperm32(r0 & 31);   // permuted LDS row (32-key groups)
    }
    const size_t lin = (size_t)head * HDIM + sc4 * 4;

    f32x4 kr0, kr1, kr2, kr3, vr0, vr1, vr2, vr3;

#define ISSUE_N(N) do {                                                  \
        const int wi_ = (N) / 3;                                         \
        const int kb_ = kb0 + (int)((dpk >> (wi_ * 16)) & 0xFFFFULL)     \
                            + 4608 * ((N) - wi_ * 3);                    \
        const size_t a0 = (size_t)(kb_ + toff0) * ROWF + lin;            \
        const size_t a1 = (size_t)(kb_ + toff1) * ROWF + lin;            \
        const size_t a2 = (size_t)(kb_ + toff2) * ROWF + lin;            \
        const size_t a3 = (size_t)(kb_ + toff3) * ROWF + lin;            \
        kr0 = *(const f32x4*)(kg + a0); vr0 = *(const f32x4*)(vg + a0);  \
        kr1 = *(const f32x4*)(kg + a1); vr1 = *(const f32x4*)(vg + a1);  \
        kr2 = *(const f32x4*)(kg + a2); vr2 = *(const f32x4*)(vg + a2);  \
        kr3 = *(const f32x4*)(kg + a3); vr3 = *(const f32x4*)(vg + a3);  \
    } while (0)

#define COMMIT() do {                                                        \
        _Pragma("unroll")                                                    \
        for (int j = 0; j < 4; ++j) {                                        \
            const int kr_ = krow0 + j;                                       \
            const int ko_ = kr_ * 64 +                                       \
                (((sc4 >> 1) ^ ((kr_ >> 1) & 7)) << 3) + ((sc4 & 1) << 2);   \
            const f32x4 kv = (j == 0) ? kr0 : (j == 1) ? kr1                 \
                             : (j == 2) ? kr2 : kr3;                         \
            *(half4*)&Klds[ko_] = pack4(kv[0], kv[1], kv[2], kv[3]);         \
        }                                                                    \
        _Pragma("unroll")                                                    \
        for (int e = 0; e < 4; ++e) {                                        \
            const int vr_ = sc4 * 4 + e;                                     \
            const int vo_ = vr_ * 128 +                                      \
                (((r4 >> 1) ^ ((vr_ >> 1) & 7)) << 3) + ((r4 & 1) << 2);     \
            *(half4*)&Vlds[vo_] = pack4(vr0[e], vr1[e], vr2[e], vr3[e]);     \
        }                                                                    \
    } while (0)

    ISSUE_N(0);

    for (int ci = 0; ci < NC; ++ci) {
        COMMIT();          // vmcnt satisfied: loads issued >=1 compute phase ago
        __syncthreads();
        if (ci + 1 < NC) ISSUE_N(ci + 1);   // overlap next chunk's HBM latency

        #pragma unroll
        for (int s = 0; s < 4; ++s) {       // four 32-key sub-blocks
            // --- S^T - m = K*Q^T + C(-m); kf read ONCE, used by all 3 mt ---
            f32x4 sacc[3][2];
            #pragma unroll
            for (int mt = 0; mt < 3; ++mt) {
                const float nm = -m_r[mt];
                sacc[mt][0] = (f32x4){nm, nm, nm, nm};
                sacc[mt][1] = (f32x4){nm, nm, nm, nm};
            }
            #pragma unroll
            for (int kc = 0; kc < 2; ++kc) {
                #pragma unroll
                for (int jt = 0; jt < 2; ++jt) {
                    const half8 kf = *(const half8*)
                        &Klds[(s * 32 + jt * 16 + c) * 64 + (((kc * 4 + g) ^ csw) << 3)];
                    #pragma unroll
                    for (int mt = 0; mt < 3; ++mt)
                        sacc[mt][jt] = __builtin_amdgcn_mfma_f32_16x16x32_f16(
                            kf, qf[mt][kc], sacc[mt][jt], 0, 0, 0);
                }
            }

            // --- softmax per mt: exp2 first; max3-fused tree + vote in parallel ---
            half8 pa[3];
            #pragma unroll
            for (int mt = 0; mt < 3; ++mt) {
                float p0 = fexp2(sacc[mt][0][0]), p1 = fexp2(sacc[mt][0][1]);
                float p2 = fexp2(sacc[mt][0][2]), p3 = fexp2(sacc[mt][0][3]);
                float p4 = fexp2(sacc[mt][1][0]), p5 = fexp2(sacc[mt][1][1]);
                float p6 = fexp2(sacc[mt][1][2]), p7 = fexp2(sacc[mt][1][3]);
                // max3-fusable chains: (((a max b) max c) ...) -> v_max3
                const float ma = fmaxf(fmaxf(fmaxf(sacc[mt][0][0], sacc[mt][0][1]),
                                             sacc[mt][0][2]), sacc[mt][0][3]);
                const float mm = fmaxf(fmaxf(fmaxf(fmaxf(ma, sacc[mt][1][0]),
                                             sacc[mt][1][1]), sacc[mt][1][2]),
                                       sacc[mt][1][3]);

                if (__builtin_expect(!__all(mm <= 12.f), 0)) {
                    // slow path: row-max reduce, shift anchor, rescale p and state
                    float mrow = mm;
                    mrow = fmaxf(mrow, __shfl_xor(mrow, 16, 64));
                    mrow = fmaxf(mrow, __shfl_xor(mrow, 32, 64));
                    const float delta = fmaxf(mrow, 0.f);
                    const float alpha = fexp2(-delta);   // row q=c
                    m_r[mt] += delta;
                    p0 *= alpha; p1 *= alpha; p2 *= alpha; p3 *= alpha;
                    p4 *= alpha; p5 *= alpha; p6 *= alpha; p7 *= alpha;
                    float ar[4];
                    #pragma unroll
                    for (int r = 0; r < 4; ++r) ar[r] = __shfl(alpha, g * 4 + r, 16);
                    #pragma unroll
                    for (int r = 0; r < 4; ++r) {
                        lacc[mt][r] *= ar[r];
                        #pragma unroll
                        for (int dt = 0; dt < 4; ++dt)
                            oacc[mt][dt][r] *= ar[r];
                    }
                }

                pa[mt] = pack8(p0, p1, p2, p3, p4, p5, p6, p7);
            }

            // --- l += P*ones (MFMA pipe); O += P V (vb read ONCE per dt) ---
            #pragma unroll
            for (int mt = 0; mt < 3; ++mt)
                lacc[mt] = __builtin_amdgcn_mfma_f32_16x16x32_f16(
                    pa[mt], ones8, lacc[mt], 0, 0, 0);
            #pragma unroll
            for (int dt = 0; dt < 4; ++dt) {
                const half8 vb = *(const half8*)
                    &Vlds[(dt * 16 + c) * 128 + ((((s << 2) | g) ^ csw) << 3)];
                #pragma unroll
                for (int mt = 0; mt < 3; ++mt)
                    oacc[mt][dt] = __builtin_amdgcn_mfma_f32_16x16x32_f16(
                        pa[mt], vb, oacc[mt][dt], 0, 0, 0);
            }
        }
        __syncthreads();
    }
#undef ISSUE_N
#undef COMMIT

    // --- epilogue: lacc already in oacc row domain; normalize, scatter via untile ---
    #pragma unroll
    for (int mt = 0; mt < 3; ++mt) {
        #pragma unroll
        for (int r = 0; r < 4; ++r) {
            const int j = wave * 48 + mt * 16 + g * 4 + r;
            float* op = out + (size_t)(tbase + intra_off(j)) * ROWF + head * HDIM;
            const float linv = __builtin_amdgcn_rcpf(lacc[mt][r]);
            #pragma unroll
            for (int dt = 0; dt < 4; ++dt)
                op[dt * 16 + c] = oacc[mt][dt][r] * linv;
        }
    }
}

extern "C" void kernel_launch(void* const* d_in, const int* in_sizes, int n_in,
                              void* d_out, int out_size, void* d_ws, size_t ws_size,
                              hipStream_t stream) {
    const float* q = (const float*)d_in[0];
    const float* k = (const float*)d_in[1];
    const float* v = (const float*)d_in[2];
    float* o = (float*)d_out;
    dim3 grid(216 * 4);     // head-major, heavy head first (round-18 proven)
    dim3 block(512);        // 8 waves x 48 q-rows = 384
    hipLaunchKernelGGL(sta_kernel, grid, block, 0, stream, q, k, v, o);
}